// Round 13
// baseline (219.639 us; speedup 1.0000x reference)
//
#include <hip/hip_runtime.h>

// Depthwise separable 4x4 FIR blur (StyleGAN2 upfirdn2d, up=down=1, pad=(2,2)).
// x: [B,C,256,256] f32, kernel: [4,4] f32 separable, out: [B,C,257,257] f32.
//
// out[q] = H[q+1] + v1*H[q] + v2*H[q-1] + v3*H[q-2],  H[r][c] = sum_j w[j]*x[r][c+1-j]
//
// R13 = R12 ladder, step 3: 64-ROW GROUPS, 1024-thread blocks (16 waves).
//   - read amplification 35/32=1.094x -> 67/64=1.047x
//   - barriers per output row halved again
//   - LDS 67x260x4 = 69.7 KB -> 2 blocks/CU x 16 waves = full 32 waves/CU
//   - sweep preserved: 512 blocks stride 8192 tasks (16/block), instantaneous
//     window = 512 consecutive tasks = contiguous ~128-plane (~33MB) chunk.
// Ladder so far (L2-side service model ~5.5 TB/s): R8 235us (amp 1.75x) ->
// R11 217.6 (1.19x) -> R12 210.6 (1.094x) -> predicted ~205 here (1.047x).
// Plain stores (NT regressed R4+R10). Shfl halo. Conflict-free LDS layout.

#define IW 256
#define IH 256
#define OW 257
#define OH 257
#define HSTR 260          // LDS H-row stride in floats (1040B, 16B-aligned rows)
#define NSLOT 67          // H[a-2 .. a+64]

typedef float f4u __attribute__((vector_size(16), aligned(4)));

__device__ __forceinline__ float sbc(float v) {   // wave-uniform -> SGPR
    return __uint_as_float(__builtin_amdgcn_readfirstlane(__float_as_uint(v)));
}

__global__ __launch_bounds__(1024) void blur_fir_kernel(
    const float* __restrict__ x,
    const float* __restrict__ k2d,
    float* __restrict__ out,
    int ntasks, int nstride)
{
    __shared__ float Hs[NSLOT * HSTR];             // 69.7 KB

    const int lane = threadIdx.x & 63;
    const int wv   = threadIdx.x >> 6;             // 0..15

    const float w0 = sbc(k2d[0]);
    const float w1 = sbc(k2d[1]);
    const float w2 = sbc(k2d[2]);
    const float w3 = sbc(k2d[3]);
    const float inv = 1.0f / w0;
    const float v1 = sbc(k2d[4]  * inv);
    const float v2 = sbc(k2d[8]  * inv);
    const float v3 = sbc(k2d[12] * inv);

    const int   c0 = lane << 2;                    // 4 cols per lane
    const float mL = (lane > 0)  ? 1.0f : 0.0f;
    const float mR = (lane < 63) ? 1.0f : 0.0f;
    const int   lm = (lane > 0)  ? lane - 1 : 0;
    const int   lp = (lane < 63) ? lane + 1 : 63;
    const bool last = (lane == 63);

    for (int t = blockIdx.x; t < ntasks; t += nstride) {
        const int plane = t >> 2;                  // 4 groups per plane
        const int rg    = t & 3;
        const int a     = rg << 6;                 // first output row of group
        const float* xp = x + ((size_t)plane << 16);

        __syncthreads();                           // prev iteration done reading Hs

        // Phase 1: H slots j = wv, wv+16, ... (<67); slot j = H[a-2+j].
        // Each input row loaded ONCE (one float4/lane), halo via shfl.
        #pragma unroll
        for (int j = wv; j < NSLOT; j += 16) {
            const int r = a - 2 + j;
            int rr = min(max(r, 0), IH - 1);       // clamp; mask below
            float4 Bv = *(const float4*)(xp + (rr << 8) + c0);
            float rm = (r >= 0 && r < IH) ? 1.0f : 0.0f;
            float lx = __shfl(Bv.z, lm, 64) * mL;  // x[r][c0-2]
            float ly = __shfl(Bv.w, lm, 64) * mL;  // x[r][c0-1]
            float rv = __shfl(Bv.x, lp, 64) * mR;  // x[r][c0+4]
            float4 h;
            h.x = w0 * Bv.y + w1 * Bv.x + w2 * ly   + w3 * lx;
            h.y = w0 * Bv.z + w1 * Bv.y + w2 * Bv.x + w3 * ly;
            h.z = w0 * Bv.w + w1 * Bv.z + w2 * Bv.y + w3 * Bv.x;
            h.w = w0 * rv   + w1 * Bv.w + w2 * Bv.z + w3 * Bv.y;
            float h4 = (w2 * Bv.w + w3 * Bv.z) * rm;   // col 256 (lane 63)
            h.x *= rm; h.y *= rm; h.z *= rm; h.w *= rm;
            float* hp = Hs + j * HSTR;
            *(float4*)(hp + c0) = h;               // 16B-aligned, conflict-free
            if (last) hp[256] = h4;
        }
        __syncthreads();

        // Phase 2: wave wv -> output rows a+4wv .. a+4wv+3 from slots 4wv..4wv+6.
        const int j0 = wv << 2;
        const float* hb = Hs + j0 * HSTR + c0;
        float4 h0 = *(const float4*)(hb           );
        float4 h1 = *(const float4*)(hb +     HSTR);
        float4 h2 = *(const float4*)(hb + 2 * HSTR);
        float4 h3 = *(const float4*)(hb + 3 * HSTR);
        float4 h4 = *(const float4*)(hb + 4 * HSTR);
        float4 h5 = *(const float4*)(hb + 5 * HSTR);
        float4 h6 = *(const float4*)(hb + 6 * HSTR);

        auto vcomb = [&](float4 A, float4 B, float4 C, float4 D) -> float4 {
            float4 r;
            r.x = A.x + v1 * B.x + v2 * C.x + v3 * D.x;
            r.y = A.y + v1 * B.y + v2 * C.y + v3 * D.y;
            r.z = A.z + v1 * B.z + v2 * C.z + v3 * D.z;
            r.w = A.w + v1 * B.w + v2 * C.w + v3 * D.w;
            return r;
        };

        float* op = out + (size_t)plane * (OW * OH)
                        + (size_t)(a + (wv << 2)) * OW + c0;
        float4 R0 = vcomb(h3, h2, h1, h0);         // row a+4wv
        float4 R1 = vcomb(h4, h3, h2, h1);
        float4 R2 = vcomb(h5, h4, h3, h2);
        float4 R3 = vcomb(h6, h5, h4, h3);
        *(f4u*)(op         ) = (f4u){R0.x, R0.y, R0.z, R0.w};
        *(f4u*)(op +     OW) = (f4u){R1.x, R1.y, R1.z, R1.w};
        *(f4u*)(op + 2 * OW) = (f4u){R2.x, R2.y, R2.z, R2.w};
        *(f4u*)(op + 3 * OW) = (f4u){R3.x, R3.y, R3.z, R3.w};
        if (last) {
            const float* sp = Hs + j0 * HSTR + 256;
            float s0 = sp[0],        s1 = sp[HSTR],     s2 = sp[2 * HSTR];
            float s3 = sp[3 * HSTR], s4 = sp[4 * HSTR], s5 = sp[5 * HSTR];
            float s6 = sp[6 * HSTR];
            op[4]          = s3 + v1 * s2 + v2 * s1 + v3 * s0;
            op[OW + 4]     = s4 + v1 * s3 + v2 * s2 + v3 * s1;
            op[2 * OW + 4] = s5 + v1 * s4 + v2 * s3 + v3 * s2;
            op[3 * OW + 4] = s6 + v1 * s5 + v2 * s4 + v3 * s3;
        }

        // Output row 256 (only group 3, wave 15): H[256]=H[257]=0.
        if (rg == 3 && wv == 15) {
            float4 Hm2 = *(const float4*)(Hs + 64 * HSTR + c0);  // H[254]
            float4 Hm1 = *(const float4*)(Hs + 65 * HSTR + c0);  // H[255]
            float4 R;
            R.x = v2 * Hm1.x + v3 * Hm2.x;
            R.y = v2 * Hm1.y + v3 * Hm2.y;
            R.z = v2 * Hm1.z + v3 * Hm2.z;
            R.w = v2 * Hm1.w + v3 * Hm2.w;
            *(f4u*)(op + 4 * OW) = (f4u){R.x, R.y, R.z, R.w};
            if (last)
                op[4 * OW + 4] = v2 * Hs[65 * HSTR + 256] + v3 * Hs[64 * HSTR + 256];
        }
    }
}

extern "C" void kernel_launch(void* const* d_in, const int* in_sizes, int n_in,
                              void* d_out, int out_size, void* d_ws, size_t ws_size,
                              hipStream_t stream) {
    const float* x   = (const float*)d_in[0];
    const float* k2d = (const float*)d_in[1];
    float* out = (float*)d_out;

    int nplanes = in_sizes[0] >> 16;               // B*C = 2048
    int ntasks  = nplanes * 4;                     // 8192 64-row group tasks
    int nblocks = 512;                             // 8192 waves, 16 tasks/block

    blur_fir_kernel<<<nblocks, 1024, 0, stream>>>(x, k2d, out, ntasks, nblocks);
}

// Round 14
// 214.923 us; speedup vs baseline: 1.0219x; 1.0219x over previous
//
#include <hip/hip_runtime.h>

// Depthwise separable 4x4 FIR blur (StyleGAN2 upfirdn2d, up=down=1, pad=(2,2)).
// x: [B,C,256,256] f32, kernel: [4,4] f32 separable, out: [B,C,257,257] f32.
//
// out[q] = H[q+1] + v1*H[q] + v2*H[q-1] + v3*H[q-2],  H[r][c] = sum_j w[j]*x[r][c+1-j]
//
// R14 = R12 (best, 210.6us: 32-row groups, 512-thr blocks, sweep, coop LDS)
// + CROSS-TASK LOAD PIPELINING. R13's regression (2 blocks/CU -> 219us)
// showed the barrier-enclosed global-load latency is materially exposed:
// phase 2 waits on the block's slowest row load. Here the 5 raw rows for
// task t+stride are issued at the START of phase 2 of task t (held in
// registers across the iteration) and consumed by the next H-compute —
// latency hides under phase-2 LDS reads/FMAs/stores + next H-compute,
// not under the barrier.
// Everything else identical to R12: amp 1.094x, LDS 36.4KB -> 4 blocks/CU
// = full 32 waves/CU, plain stores, shfl halo, conflict-free LDS layout.

#define IW 256
#define IH 256
#define OW 257
#define OH 257
#define HSTR 260          // LDS H-row stride in floats (1040B, 16B-aligned rows)
#define NSLOT 35          // H[a-2 .. a+32]

typedef float f4u __attribute__((vector_size(16), aligned(4)));

__device__ __forceinline__ float sbc(float v) {   // wave-uniform -> SGPR
    return __uint_as_float(__builtin_amdgcn_readfirstlane(__float_as_uint(v)));
}

__global__ __launch_bounds__(512) void blur_fir_kernel(
    const float* __restrict__ x,
    const float* __restrict__ k2d,
    float* __restrict__ out,
    int ntasks, int nstride)
{
    __shared__ float Hs[NSLOT * HSTR];             // 36.4 KB

    const int lane = threadIdx.x & 63;
    const int wv   = threadIdx.x >> 6;             // 0..7

    const float w0 = sbc(k2d[0]);
    const float w1 = sbc(k2d[1]);
    const float w2 = sbc(k2d[2]);
    const float w3 = sbc(k2d[3]);
    const float inv = 1.0f / w0;
    const float v1 = sbc(k2d[4]  * inv);
    const float v2 = sbc(k2d[8]  * inv);
    const float v3 = sbc(k2d[12] * inv);

    const int   c0 = lane << 2;                    // 4 cols per lane
    const float mL = (lane > 0)  ? 1.0f : 0.0f;
    const float mR = (lane < 63) ? 1.0f : 0.0f;
    const int   lm = (lane > 0)  ? lane - 1 : 0;
    const int   lp = (lane < 63) ? lane + 1 : 63;
    const bool last = (lane == 63);

    // Wave's H slots: j = wv + 8k, k=0..4 (k=4 only for wv<3).
    const int  j4ok = (wv + 32 < NSLOT);

    // Issue the 5 raw-row loads for task tt into G registers.
    auto issue = [&](int tt, float4& G0, float4& G1, float4& G2,
                     float4& G3, float4& G4) {
        const int plane = tt >> 3;
        const int a     = (tt & 7) << 5;
        const float* xp = x + ((size_t)plane << 16);
        auto ld = [&](int j) -> float4 {
            int r  = a - 2 + j;
            int rr = min(max(r, 0), IH - 1);
            return *(const float4*)(xp + (rr << 8) + c0);
        };
        G0 = ld(wv);
        G1 = ld(wv + 8);
        G2 = ld(wv + 16);
        G3 = ld(wv + 24);
        G4 = j4ok ? ld(wv + 32) : G3;
    };

    int t = blockIdx.x;
    float4 G0, G1, G2, G3, G4;
    if (t < ntasks) issue(t, G0, G1, G2, G3, G4);

    for (; t < ntasks; t += nstride) {
        const int plane = t >> 3;                  // 8 groups per plane
        const int rg    = t & 7;
        const int a     = rg << 5;                 // first output row of group

        // H-compute for held rows (register-only: shfl + FMA).
        float4 Hv[5]; float h4s[5];
        {
            auto hc = [&](float4 Bv, int r, float4& h, float& h4) {
                float rm = (r >= 0 && r < IH) ? 1.0f : 0.0f;
                float lx = __shfl(Bv.z, lm, 64) * mL;
                float ly = __shfl(Bv.w, lm, 64) * mL;
                float rv = __shfl(Bv.x, lp, 64) * mR;
                h.x = w0 * Bv.y + w1 * Bv.x + w2 * ly   + w3 * lx;
                h.y = w0 * Bv.z + w1 * Bv.y + w2 * Bv.x + w3 * ly;
                h.z = w0 * Bv.w + w1 * Bv.z + w2 * Bv.y + w3 * Bv.x;
                h.w = w0 * rv   + w1 * Bv.w + w2 * Bv.z + w3 * Bv.y;
                h4  = (w2 * Bv.w + w3 * Bv.z) * rm;
                h.x *= rm; h.y *= rm; h.z *= rm; h.w *= rm;
            };
            hc(G0, a - 2 + wv,      Hv[0], h4s[0]);
            hc(G1, a - 2 + wv + 8,  Hv[1], h4s[1]);
            hc(G2, a - 2 + wv + 16, Hv[2], h4s[2]);
            hc(G3, a - 2 + wv + 24, Hv[3], h4s[3]);
            hc(G4, a - 2 + wv + 32, Hv[4], h4s[4]);
        }

        __syncthreads();                           // prev phase-2 readers done

        #pragma unroll
        for (int k = 0; k < 5; ++k) {
            const int j = wv + (k << 3);
            if (k < 4 || j4ok) {
                float* hp = Hs + j * HSTR;
                *(float4*)(hp + c0) = Hv[k];       // 16B-aligned, conflict-free
                if (last) hp[256] = h4s[k];
            }
        }
        __syncthreads();

        // Pipeline: issue next task's raw-row loads NOW (consumed next iter).
        {
            int tn = t + nstride;
            if (tn < ntasks) issue(tn, G0, G1, G2, G3, G4);
        }

        // Phase 2: wave wv -> output rows a+4wv..a+4wv+3 from slots 4wv..4wv+6.
        const int j0 = wv << 2;
        const float* hb = Hs + j0 * HSTR + c0;
        float4 h0 = *(const float4*)(hb           );
        float4 h1 = *(const float4*)(hb +     HSTR);
        float4 h2 = *(const float4*)(hb + 2 * HSTR);
        float4 h3 = *(const float4*)(hb + 3 * HSTR);
        float4 h4 = *(const float4*)(hb + 4 * HSTR);
        float4 h5 = *(const float4*)(hb + 5 * HSTR);
        float4 h6 = *(const float4*)(hb + 6 * HSTR);

        auto vcomb = [&](float4 A, float4 B, float4 C, float4 D) -> float4 {
            float4 r;
            r.x = A.x + v1 * B.x + v2 * C.x + v3 * D.x;
            r.y = A.y + v1 * B.y + v2 * C.y + v3 * D.y;
            r.z = A.z + v1 * B.z + v2 * C.z + v3 * D.z;
            r.w = A.w + v1 * B.w + v2 * C.w + v3 * D.w;
            return r;
        };

        float* op = out + (size_t)plane * (OW * OH)
                        + (size_t)(a + (wv << 2)) * OW + c0;
        float4 R0 = vcomb(h3, h2, h1, h0);         // row a+4wv
        float4 R1 = vcomb(h4, h3, h2, h1);
        float4 R2 = vcomb(h5, h4, h3, h2);
        float4 R3 = vcomb(h6, h5, h4, h3);
        *(f4u*)(op         ) = (f4u){R0.x, R0.y, R0.z, R0.w};
        *(f4u*)(op +     OW) = (f4u){R1.x, R1.y, R1.z, R1.w};
        *(f4u*)(op + 2 * OW) = (f4u){R2.x, R2.y, R2.z, R2.w};
        *(f4u*)(op + 3 * OW) = (f4u){R3.x, R3.y, R3.z, R3.w};
        if (last) {
            const float* sp = Hs + j0 * HSTR + 256;
            float s0 = sp[0],        s1 = sp[HSTR],     s2 = sp[2 * HSTR];
            float s3 = sp[3 * HSTR], s4 = sp[4 * HSTR], s5 = sp[5 * HSTR];
            float s6 = sp[6 * HSTR];
            op[4]          = s3 + v1 * s2 + v2 * s1 + v3 * s0;
            op[OW + 4]     = s4 + v1 * s3 + v2 * s2 + v3 * s1;
            op[2 * OW + 4] = s5 + v1 * s4 + v2 * s3 + v3 * s2;
            op[3 * OW + 4] = s6 + v1 * s5 + v2 * s4 + v3 * s3;
        }

        // Output row 256 (only group 7, wave 7): H[256]=H[257]=0.
        if (rg == 7 && wv == 7) {
            float4 Hm2 = *(const float4*)(Hs + 32 * HSTR + c0);  // H[254]
            float4 Hm1 = *(const float4*)(Hs + 33 * HSTR + c0);  // H[255]
            float4 R;
            R.x = v2 * Hm1.x + v3 * Hm2.x;
            R.y = v2 * Hm1.y + v3 * Hm2.y;
            R.z = v2 * Hm1.z + v3 * Hm2.z;
            R.w = v2 * Hm1.w + v3 * Hm2.w;
            *(f4u*)(op + 4 * OW) = (f4u){R.x, R.y, R.z, R.w};
            if (last)
                op[4 * OW + 4] = v2 * Hs[33 * HSTR + 256] + v3 * Hs[32 * HSTR + 256];
        }
    }
}

extern "C" void kernel_launch(void* const* d_in, const int* in_sizes, int n_in,
                              void* d_out, int out_size, void* d_ws, size_t ws_size,
                              hipStream_t stream) {
    const float* x   = (const float*)d_in[0];
    const float* k2d = (const float*)d_in[1];
    float* out = (float*)d_out;

    int nplanes = in_sizes[0] >> 16;               // B*C = 2048
    int ntasks  = nplanes * 8;                     // 16384 32-row group tasks
    int nblocks = 1024;                            // 8192 waves, 16 tasks/block

    blur_fir_kernel<<<nblocks, 512, 0, stream>>>(x, k2d, out, ntasks, nblocks);
}

// Round 15
// 210.889 us; speedup vs baseline: 1.0415x; 1.0191x over previous
//
#include <hip/hip_runtime.h>

// Depthwise separable 4x4 FIR blur (StyleGAN2 upfirdn2d, up=down=1, pad=(2,2)).
// x: [B,C,256,256] f32, kernel: [4,4] f32 separable, out: [B,C,257,257] f32.
//
// out[q] = H[q+1] + v1*H[q] + v2*H[q-1] + v3*H[q-2],  H[r][c] = sum_j w[j]*x[r][c+1-j]
//
// R15 = R12 + ROLLING H-RING (amp 1.094x -> 1.012x).
// Block walks a plane's 8 32-row chunks SEQUENTIALLY with H kept in a
// 36-slot LDS ring (slot(r) = (r+2) % 36). Chunk k>=1 computes only the 32
// NEW rows (a+1..a+32); the 3 boundary rows a-2..a are still live in the
// ring from chunk k-1 (36-slot ring >= 35-row window; write/read slot
// disjointness verified mod 36). Per plane: 35 + 7*32 = 259 row loads vs
// R12's 280. Waves load 4 CONTIGUOUS rows per chunk (4KB burst, vs R12's
// stride-8). LDS 36*260*4 = 37.4 KB -> 4 blocks/CU = full 32 waves/CU.
// Grid 1024 blocks x 2 planes, lockstep walk -> compact ~38MB read front.
// Barriers: 2 per chunk, same rate as R12. Plain stores, shfl halo.

#define IW 256
#define IH 256
#define OW 257
#define OH 257
#define HSTR 260          // LDS H-row stride in floats (1040B, 16B-aligned rows)
#define RING 36           // H ring slots

typedef float f4u __attribute__((vector_size(16), aligned(4)));

__device__ __forceinline__ float sbc(float v) {   // wave-uniform -> SGPR
    return __uint_as_float(__builtin_amdgcn_readfirstlane(__float_as_uint(v)));
}

__global__ __launch_bounds__(512) void blur_fir_kernel(
    const float* __restrict__ x,
    const float* __restrict__ k2d,
    float* __restrict__ out,
    int nplanes, int pstride)
{
    __shared__ float Hs[RING * HSTR];              // 37.44 KB

    const int lane = threadIdx.x & 63;
    const int wv   = threadIdx.x >> 6;             // 0..7

    const float w0 = sbc(k2d[0]);
    const float w1 = sbc(k2d[1]);
    const float w2 = sbc(k2d[2]);
    const float w3 = sbc(k2d[3]);
    const float inv = 1.0f / w0;
    const float v1 = sbc(k2d[4]  * inv);
    const float v2 = sbc(k2d[8]  * inv);
    const float v3 = sbc(k2d[12] * inv);

    const int   c0 = lane << 2;                    // 4 cols per lane
    const float mL = (lane > 0)  ? 1.0f : 0.0f;
    const float mR = (lane < 63) ? 1.0f : 0.0f;
    const int   lm = (lane > 0)  ? lane - 1 : 0;
    const int   lp = (lane < 63) ? lane + 1 : 63;
    const bool last = (lane == 63);

    for (int plane = blockIdx.x; plane < nplanes; plane += pstride) {
        const float* xp   = x   + ((size_t)plane << 16);
        float*       outp = out + (size_t)plane * (OW * OH);

        for (int k = 0; k < 8; ++k) {
            const int a = k << 5;                  // first output row of chunk

            // Rows this wave computes: chunk 0 -> 35 rows (-2..32) split 5/5/5/4..;
            // chunks 1..7 -> 32 new rows (a+1..a+32), 4 contiguous per wave.
            int n0, cnt;
            if (k == 0) {
                n0  = (wv < 3) ? (5 * wv - 2) : ((wv << 2) + 1);
                cnt = (wv < 3) ? 5 : 4;
            } else {
                n0  = a + 1 + (wv << 2);
                cnt = 4;
            }

            // Issue loads (land under the barrier + previous chunk's tail).
            float4 Bv[5];
            #pragma unroll
            for (int q = 0; q < 5; ++q) {
                if (q < cnt) {
                    int r  = n0 + q;
                    int rr = min(max(r, 0), IH - 1);
                    Bv[q] = *(const float4*)(xp + (rr << 8) + c0);
                }
            }

            __syncthreads();                       // prev chunk's readers done

            const int s0 = (n0 + 2) % RING;        // wave-uniform ring slot base
            #pragma unroll
            for (int q = 0; q < 5; ++q) {
                if (q < cnt) {
                    const int r = n0 + q;
                    float rm = (r >= 0 && r < IH) ? 1.0f : 0.0f;
                    float4 B = Bv[q];
                    float lx = __shfl(B.z, lm, 64) * mL;   // x[r][c0-2]
                    float ly = __shfl(B.w, lm, 64) * mL;   // x[r][c0-1]
                    float rv = __shfl(B.x, lp, 64) * mR;   // x[r][c0+4]
                    float4 h;
                    h.x = w0 * B.y + w1 * B.x + w2 * ly  + w3 * lx;
                    h.y = w0 * B.z + w1 * B.y + w2 * B.x + w3 * ly;
                    h.z = w0 * B.w + w1 * B.z + w2 * B.y + w3 * B.x;
                    h.w = w0 * rv  + w1 * B.w + w2 * B.z + w3 * B.y;
                    float h4 = (w2 * B.w + w3 * B.z) * rm; // col 256 (lane 63)
                    h.x *= rm; h.y *= rm; h.z *= rm; h.w *= rm;
                    int sq = s0 + q; if (sq >= RING) sq -= RING;
                    float* hp = Hs + sq * HSTR;
                    *(float4*)(hp + c0) = h;               // conflict-free
                    if (last) hp[256] = h4;
                }
            }
            __syncthreads();

            // Phase 2: wave wv -> out rows a+4wv..a+4wv+3 from H rows
            // a+4wv-2 .. a+4wv+4 (ring slots t0..t0+6).
            const int t0 = (a + (wv << 2)) % RING;  // slot of row a+4wv-2
            float4 h[7];
            #pragma unroll
            for (int q = 0; q < 7; ++q) {
                int sq = t0 + q; if (sq >= RING) sq -= RING;
                h[q] = *(const float4*)(Hs + sq * HSTR + c0);
            }

            auto vcomb = [&](float4 A, float4 B, float4 C, float4 D) -> float4 {
                float4 r;
                r.x = A.x + v1 * B.x + v2 * C.x + v3 * D.x;
                r.y = A.y + v1 * B.y + v2 * C.y + v3 * D.y;
                r.z = A.z + v1 * B.z + v2 * C.z + v3 * D.z;
                r.w = A.w + v1 * B.w + v2 * C.w + v3 * D.w;
                return r;
            };

            float* op = outp + (size_t)(a + (wv << 2)) * OW + c0;
            float4 R0 = vcomb(h[3], h[2], h[1], h[0]);     // row a+4wv
            float4 R1 = vcomb(h[4], h[3], h[2], h[1]);
            float4 R2 = vcomb(h[5], h[4], h[3], h[2]);
            float4 R3 = vcomb(h[6], h[5], h[4], h[3]);
            *(f4u*)(op         ) = (f4u){R0.x, R0.y, R0.z, R0.w};
            *(f4u*)(op +     OW) = (f4u){R1.x, R1.y, R1.z, R1.w};
            *(f4u*)(op + 2 * OW) = (f4u){R2.x, R2.y, R2.z, R2.w};
            *(f4u*)(op + 3 * OW) = (f4u){R3.x, R3.y, R3.z, R3.w};
            if (last) {
                float s[7];
                #pragma unroll
                for (int q = 0; q < 7; ++q) {
                    int sq = t0 + q; if (sq >= RING) sq -= RING;
                    s[q] = Hs[sq * HSTR + 256];
                }
                op[4]          = s[3] + v1 * s[2] + v2 * s[1] + v3 * s[0];
                op[OW + 4]     = s[4] + v1 * s[3] + v2 * s[2] + v3 * s[1];
                op[2 * OW + 4] = s[5] + v1 * s[4] + v2 * s[3] + v3 * s[2];
                op[3 * OW + 4] = s[6] + v1 * s[5] + v2 * s[4] + v3 * s[3];
            }

            // Output row 256 (chunk 7, wave 7): H[256]=H[257]=0.
            if (k == 7 && wv == 7) {
                const int sA = 256 % RING;         // slot of H[254]
                const int sB = 257 % RING;         // slot of H[255]
                float4 Hm2 = *(const float4*)(Hs + sA * HSTR + c0);
                float4 Hm1 = *(const float4*)(Hs + sB * HSTR + c0);
                float4 R;
                R.x = v2 * Hm1.x + v3 * Hm2.x;
                R.y = v2 * Hm1.y + v3 * Hm2.y;
                R.z = v2 * Hm1.z + v3 * Hm2.z;
                R.w = v2 * Hm1.w + v3 * Hm2.w;
                float* o2 = outp + (size_t)256 * OW + c0;
                *(f4u*)o2 = (f4u){R.x, R.y, R.z, R.w};
                if (last)
                    o2[4] = v2 * Hs[sB * HSTR + 256] + v3 * Hs[sA * HSTR + 256];
            }
        }
    }
}

extern "C" void kernel_launch(void* const* d_in, const int* in_sizes, int n_in,
                              void* d_out, int out_size, void* d_ws, size_t ws_size,
                              hipStream_t stream) {
    const float* x   = (const float*)d_in[0];
    const float* k2d = (const float*)d_in[1];
    float* out = (float*)d_out;

    int nplanes = in_sizes[0] >> 16;               // B*C = 2048
    int nblocks = 1024;                            // 4 blocks/CU exact; 2 planes each

    blur_fir_kernel<<<nblocks, 512, 0, stream>>>(x, k2d, out, nplanes, nblocks);
}